// Round 13
// baseline (493.211 us; speedup 1.0000x reference)
//
#include <hip/hip_runtime.h>

#define SS 2048
#define DD 1024
#define DQKV 3072
#define KP 1088            // 1024 + 16 lora-hi + 16 lora-lo + 1 bias + 31 pad
#define NT32 34            // K-tiles of 32
#define MTOT 8192
#define QKSZ ((size_t)MTOT * DD)   // floats per q/k/v plane
#define SCL 0.18033688011112042f   /* 0.125 * log2(e), folded into K plane */

typedef unsigned short us;
typedef __attribute__((ext_vector_type(8))) short bf16x8;
typedef __attribute__((ext_vector_type(4))) float f32x4;
typedef __attribute__((ext_vector_type(4))) unsigned u32x4;

#define WAITVM(N) asm volatile("s_waitcnt vmcnt(" #N ")" ::: "memory")
#define WAITLGKM0 asm volatile("s_waitcnt lgkmcnt(0)" ::: "memory")

__device__ __forceinline__ us f2bf(float f) {
    unsigned u = __float_as_uint(f);
    return (us)((u + 0x7fffu + ((u >> 16) & 1u)) >> 16);
}
__device__ __forceinline__ float bf2f(us h) { return __uint_as_float(((unsigned)h) << 16); }
__device__ __forceinline__ void split2(float q, us& h, us& l) {
    h = f2bf(q); l = f2bf(q - bf2f(h));
}
__device__ __forceinline__ unsigned cvtpk(float lo, float hi) {
    unsigned r;
    asm("v_cvt_pk_bf16_f32 %0, %1, %2" : "=v"(r) : "v"(lo), "v"(hi));
    return r;
}

// exact log-domain fake quant level: e = round(log2(clip(|x|/s, 2^-255, 1)))
// f32 candidate + exact double-MUL boundary correction (identical to double-divide version:
// r >= 2^(k-0.5)  <=>  ax^2 >= s^2 * 2^(2k-1), and ax^2 / s^2 / ldexp are exact in double)
__device__ __forceinline__ int logq_e(float ax, float s) {
    int e = 0;
    if (ax < s) {
        int ex;
        float m = frexpf(ax / s, &ex);
        int k = (m >= 0.70710678f) ? ex : ex - 1;   // f32 candidate (within +-1 of exact)
        double ax2 = (double)ax * (double)ax;       // exact
        double s2 = (double)s * (double)s;          // exact
        if (ax2 >= ldexp(s2, 2 * k + 1)) k += 1;
        else if (ax2 < ldexp(s2, 2 * k - 1)) k -= 1;
        if (k > 0) k = 0;
        e = (k < -255) ? -255 : k;
    }
    return e;
}
__device__ __forceinline__ float logq_exact(float x, float s) {
    float ax = fabsf(x);
    if (ax == 0.f) return copysignf(0.f, x);
    return copysignf(ldexpf(s, logq_e(ax, s)), x);
}

__device__ __forceinline__ void gll16(const void* g, void* l) {
    __builtin_amdgcn_global_load_lds(
        (const __attribute__((address_space(1))) void*)g,
        (__attribute__((address_space(3))) void*)l, 16, 0, 0);
}

// ---------------- scales / quant / lora prep ----------------

__global__ void k_zero(unsigned* p, int n) {
    int i = blockIdx.x * 256 + threadIdx.x;
    if (i < n) p[i] = 0u;
}

__global__ void k_colmax(const float* __restrict__ x, unsigned* __restrict__ smax) {
    int c = blockIdx.x * 256 + threadIdx.x;
    int r0 = blockIdx.y * 128;
    float m = 0.f;
    for (int r = 0; r < 128; ++r) m = fmaxf(m, fabsf(x[(size_t)(r0 + r) * DD + c]));
    atomicMax(smax + c, __float_as_uint(m));
}

// fused: quantize row (exact bf16 rep Ah) + lora cols + bias/pad; one pass over x
__global__ __launch_bounds__(256) void k_quant_lora(const float* __restrict__ x,
                                                    const unsigned* __restrict__ smax,
                                                    const float* __restrict__ lA,
                                                    us* __restrict__ xq) {
    __shared__ float red[4][16];
    int m = blockIdx.x, tx = threadIdx.x;
    int lane = tx & 63, w = tx >> 6;
    float4 xv = ((const float4*)(x + (size_t)m * DD))[tx];
    int c = tx * 4;
    float vv[4] = {xv.x, xv.y, xv.z, xv.w};
    ushort4 qh;
    us* ph = (us*)&qh;
#pragma unroll
    for (int j = 0; j < 4; ++j) {
        float s = fmaxf(__uint_as_float(smax[c + j]), 1e-8f);
        float sh = bf2f(f2bf(s));
        float ax = fabsf(vv[j]);
        if (ax == 0.f) ph[j] = (us)((__float_as_uint(vv[j]) >> 16) & 0x8000u);
        else ph[j] = f2bf(copysignf(ldexpf(sh, logq_e(ax, s)), vv[j]));
    }
    *(ushort4*)(xq + (size_t)m * KP + c) = qh;
    // lora partial: acc[r] = sum over this thread's 4 cols of x*lA
    float acc[16];
#pragma unroll
    for (int r = 0; r < 16; ++r) acc[r] = 0.f;
#pragma unroll
    for (int j = 0; j < 4; ++j) {
        float xs = vv[j];
        const float4* lr = (const float4*)(lA + (size_t)(c + j) * 16);
        float4 a0 = lr[0], a1 = lr[1], a2 = lr[2], a3 = lr[3];
        acc[0] += xs * a0.x; acc[1] += xs * a0.y; acc[2] += xs * a0.z; acc[3] += xs * a0.w;
        acc[4] += xs * a1.x; acc[5] += xs * a1.y; acc[6] += xs * a1.z; acc[7] += xs * a1.w;
        acc[8] += xs * a2.x; acc[9] += xs * a2.y; acc[10] += xs * a2.z; acc[11] += xs * a2.w;
        acc[12] += xs * a3.x; acc[13] += xs * a3.y; acc[14] += xs * a3.z; acc[15] += xs * a3.w;
    }
#pragma unroll
    for (int msk = 1; msk < 64; msk <<= 1)
#pragma unroll
        for (int r = 0; r < 16; ++r) acc[r] += __shfl_xor(acc[r], msk);
    if (lane == 0)
#pragma unroll
        for (int r = 0; r < 16; ++r) red[w][r] = acc[r];
    __syncthreads();
    if (tx < 16) {
        float v = 2.0f * (red[0][tx] + red[1][tx] + red[2][tx] + red[3][tx]);
        us h, l; split2(v, h, l);
        xq[(size_t)m * KP + 1024 + tx] = h;
        xq[(size_t)m * KP + 1040 + tx] = l;
    } else if (tx == 16) {
        xq[(size_t)m * KP + 1056] = 0x3F80;   // bias col = 1.0
    } else if (tx < 48) {
        xq[(size_t)m * KP + 1040 + tx] = 0;   // pads 1057..1087
    }
}

// weight quant + fold activation-scale residual: W' = Wq*(1+rho_c); split hi/lo.
__global__ __launch_bounds__(256) void k_quant_w(const float* __restrict__ W, const float* __restrict__ lB,
                                                 const float* __restrict__ bias,
                                                 const unsigned* __restrict__ smax,
                                                 us* __restrict__ wh, us* __restrict__ wl, int Nn) {
    __shared__ float red[4];
    int n = blockIdx.x, tx = threadIdx.x;
    int lane = tx & 63, w = tx >> 6;
    float4 wv = ((const float4*)(W + (size_t)n * DD))[tx];
    float m4 = fmaxf(fmaxf(fabsf(wv.x), fabsf(wv.y)), fmaxf(fabsf(wv.z), fabsf(wv.w)));
#pragma unroll
    for (int msk = 1; msk < 64; msk <<= 1) m4 = fmaxf(m4, __shfl_xor(m4, msk));
    if (lane == 0) red[w] = m4;
    __syncthreads();
    float t = fmaxf(fmaxf(fmaxf(red[0], red[1]), fmaxf(red[2], red[3])), 1e-8f);
    float vv[4] = {wv.x, wv.y, wv.z, wv.w};
    int c = tx * 4;
    ushort4 qh, ql;
    us* ph = (us*)&qh; us* pl = (us*)&ql;
#pragma unroll
    for (int j = 0; j < 4; ++j) {
        float s = fmaxf(__uint_as_float(smax[c + j]), 1e-8f);
        float sh = bf2f(f2bf(s));
        float rho = (s - sh) / sh;
        float q = logq_exact(vv[j], t);
        float wp = q + q * rho;
        split2(wp, ph[j], pl[j]);
    }
    *(ushort4*)(wh + (size_t)n * KP + c) = qh;
    *(ushort4*)(wl + (size_t)n * KP + c) = ql;
    if (tx < 64) {
        us h = 0, l = 0;
        if (tx < 32) { int r = tx & 15; split2(lB[(size_t)r * Nn + n], h, l); }
        else if (tx == 32) split2(bias[n], h, l);
        wh[(size_t)n * KP + 1024 + tx] = h;
        wl[(size_t)n * KP + 1024 + tx] = l;
    }
}

// ---------------- GEMM: C = Ah @ (W'h + W'l)^T, 2 MFMA passes ----------------
// 8-wave (512t) BM=256 BN=128 BK=32; 64KB LDS total -> 2 blocks/CU (16 waves);
// counted vmcnt(4); GSTAGE(t+2) issued before MFMA cluster; XOR4 swizzle (g ^= (r^r>>2)&3) both-sides.
// MODE 0: linear f32 C[M][Nn].  MODE 1: qkv epilogue — q f32, v f32, k*SCL split bf16 [bh][s][64].

template <int MODE>
__global__ __launch_bounds__(512, 4) void k_gemm(const us* __restrict__ Aq_,
                                                 const us* __restrict__ Bh_, const us* __restrict__ Bl_,
                                                 float* __restrict__ C, int Nn,
                                                 us* __restrict__ Khg, us* __restrict__ Klg,
                                                 float* __restrict__ vbuf) {
    __shared__ us LA[2][8192];     // A 256x32 bf16 per buf (32KB total)
    __shared__ us LBh[2][4096];    // Bh 128x32 (16KB)
    __shared__ us LBl[2][4096];    // Bl 128x32 (16KB)
    int tid = threadIdx.x;
    int bm = blockIdx.x, bn = blockIdx.y;
    int lane = tid & 63, w = tid >> 6;
    int wm = w >> 2, wn = w & 3;             // 2 x 4 wave grid; per-wave out 128x32
    int l15 = lane & 15, l4 = lane >> 4;
    // staging: row r = tid>>2 (128 rows/gll16), dest granule tid&3; source pre-swizzled
    int srow = tid >> 2;
    int gsrc = ((tid & 3) ^ ((srow ^ (srow >> 2)) & 3)) * 8;
    const us* aP  = Aq_ + (size_t)(bm * 256 + srow) * KP + gsrc;
    const us* bhP = Bh_ + (size_t)(bn * 128 + srow) * KP + gsrc;
    const us* blP = Bl_ + (size_t)(bn * 128 + srow) * KP + gsrc;
    f32x4 zero4 = {0.f, 0.f, 0.f, 0.f};
    f32x4 acc[8][2];
#pragma unroll
    for (int i = 0; i < 8; ++i) { acc[i][0] = zero4; acc[i][1] = zero4; }

#define GSTAGE(buf, kt)                                                  \
    do {                                                                 \
        int k0_ = (kt) * 32;                                             \
        gll16(aP + k0_,                    &LA[(buf)][0]    + tid * 8);  \
        gll16(aP + (size_t)128 * KP + k0_, &LA[(buf)][4096] + tid * 8);  \
        gll16(bhP + k0_,                   &LBh[(buf)][0]   + tid * 8);  \
        gll16(blP + k0_,                   &LBl[(buf)][0]   + tid * 8);  \
    } while (0)

    GSTAGE(0, 0);
    GSTAGE(1, 1);

    // read-side swizzle: row R = base16 + l15 -> (R ^ (R>>2))&3 == (l15 ^ (l15>>2))&3
    int gsw = ((l4 ^ ((l15 ^ (l15 >> 2)) & 3))) * 8;
    int cur = 0;
    for (int kt = 0; kt < NT32; ++kt) {
        if (kt + 1 < NT32) { WAITVM(4); } else { WAITVM(0); }   // tile kt landed (all waves after barrier)
        __builtin_amdgcn_s_barrier();
        const us* A0  = &LA[cur][0];
        const us* Bh0 = &LBh[cur][0];
        const us* Bl0 = &LBl[cur][0];
        bf16x8 a0[8], b0h[2], b0l[2];
#pragma unroll
        for (int i = 0; i < 8; ++i)
            a0[i] = *(const bf16x8*)(A0 + (wm * 128 + i * 16 + l15) * 32 + gsw);
#pragma unroll
        for (int i = 0; i < 2; ++i) {
            b0h[i] = *(const bf16x8*)(Bh0 + (wn * 32 + i * 16 + l15) * 32 + gsw);
            b0l[i] = *(const bf16x8*)(Bl0 + (wn * 32 + i * 16 + l15) * 32 + gsw);
        }
        WAITLGKM0;                           // this wave done reading buf[cur]
        __builtin_amdgcn_sched_barrier(0);
        __builtin_amdgcn_s_barrier();        // all waves done reading buf[cur]
        __builtin_amdgcn_sched_barrier(0);
        if (kt + 2 < NT32) GSTAGE(cur, kt + 2);   // restage freed buffer; overlaps MFMA below
        __builtin_amdgcn_s_setprio(1);
#pragma unroll
        for (int mi = 0; mi < 8; ++mi)
#pragma unroll
            for (int ni = 0; ni < 2; ++ni) {
                acc[mi][ni] = __builtin_amdgcn_mfma_f32_16x16x32_bf16(a0[mi], b0h[ni], acc[mi][ni], 0, 0, 0);
                acc[mi][ni] = __builtin_amdgcn_mfma_f32_16x16x32_bf16(a0[mi], b0l[ni], acc[mi][ni], 0, 0, 0);
            }
        __builtin_amdgcn_s_setprio(0);
        cur ^= 1;
    }
#undef GSTAGE

    int plane = bn >> 3;   // MODE 1 only; block-uniform
#pragma unroll
    for (int mi = 0; mi < 8; ++mi) {
#pragma unroll
        for (int ni = 0; ni < 2; ++ni) {
            int ncol = bn * 128 + wn * 32 + ni * 16 + l15;
            size_t mbase = (size_t)bm * 256 + wm * 128 + mi * 16 + l4 * 4;
#pragma unroll
            for (int rr = 0; rr < 4; ++rr) {
                float v = acc[mi][ni][rr];
                size_t m = mbase + rr;
                if (MODE == 0) {
                    C[m * (size_t)Nn + ncol] = v;
                } else {
                    int cc = ncol & 1023;
                    if (plane == 0) {
                        C[m * DD + cc] = v;
                    } else if (plane == 2) {
                        vbuf[m * DD + cc] = v;
                    } else {
                        us hh, ll; split2(v * SCL, hh, ll);   // fold softmax scale into K
                        size_t d = ((size_t)((m >> 11) * 16 + (cc >> 6)) * SS + (m & 2047)) * 64 + (cc & 63);
                        Khg[d] = hh; Klg[d] = ll;
                    }
                }
            }
        }
    }
}

// ---------------- V transpose+split: vbuf f32 -> vth/vtl [bh][hd][s-permuted] bf16 ----------------

__global__ __launch_bounds__(256) void k_transpose_v(const float* __restrict__ vbuf,
                                                     us* __restrict__ vth, us* __restrict__ vtl) {
    __shared__ us th[64][72], tl[64][72];
    int st = blockIdx.x, bh = blockIdx.y;
    int bb = bh >> 4, h = bh & 15;
    int s0 = st * 64, tid = threadIdx.x;
    int sl = tid >> 2, c0 = (tid & 3) * 16;
    const float* src = vbuf + (size_t)(bb * SS + s0 + sl) * DD + h * 64 + c0;
#pragma unroll
    for (int j4 = 0; j4 < 4; ++j4) {
        float4 v = *(const float4*)(src + j4 * 4);
        float vv[4] = {v.x, v.y, v.z, v.w};
#pragma unroll
        for (int j = 0; j < 4; ++j) {
            us hh, ll; split2(vv[j], hh, ll);
            th[c0 + j4 * 4 + j][sl] = hh;
            tl[c0 + j4 * 4 + j][sl] = ll;
        }
    }
    __syncthreads();
#pragma unroll
    for (int p = 0; p < 2; ++p) {
        int gidx = p * 256 + tid;
        int hd = gidx >> 3, g = gidx & 7;
        int base = (g >> 2) * 32 + (g & 3) * 4;
        ushort4 a, b2, c, d2;
        a.x = th[hd][base];      a.y = th[hd][base + 1];  a.z = th[hd][base + 2];  a.w = th[hd][base + 3];
        b2.x = th[hd][base + 16]; b2.y = th[hd][base + 17]; b2.z = th[hd][base + 18]; b2.w = th[hd][base + 19];
        c.x = tl[hd][base];      c.y = tl[hd][base + 1];  c.z = tl[hd][base + 2];  c.w = tl[hd][base + 3];
        d2.x = tl[hd][base + 16]; d2.y = tl[hd][base + 17]; d2.z = tl[hd][base + 18]; d2.w = tl[hd][base + 19];
        size_t dof = ((size_t)bh * 64 + hd) * SS + s0 + g * 8;
        *(ushort4*)(vth + dof) = a;  *(ushort4*)(vth + dof + 4) = b2;
        *(ushort4*)(vtl + dof) = c;  *(ushort4*)(vtl + dof + 4) = d2;
    }
}

// ---------------- causal flash attention; 8 waves x 16 q-rows (128/block); counted-vmcnt; defer-max ----
// output written IN-PLACE into the q plane; K plane pre-scaled by SCL.
// grid (64 bh, 16 y), qt = 15-y (heavy first); 1024 blocks = 2 dispatch rounds -> dynamic balance.

__global__ __launch_bounds__(512, 2) void k_attn(float* qo,
                                                 const us* __restrict__ Khg, const us* __restrict__ Klg,
                                                 const us* __restrict__ vth, const us* __restrict__ vtl) {
    __shared__ us L[2][16384];  // per buf: [0]=Kh [4096]=Kl [8192]=Vh [12288]=Vl, 64x64 bf16, XOR-8 swz
    int bh = blockIdx.x;
    int qt = (int)(gridDim.y - 1) - blockIdx.y;   // heavy q-tiles first
    int b = bh >> 4, h = bh & 15;
    int q0 = qt * 128;
    int tid = threadIdx.x, w = tid >> 6, lane = tid & 63;
    int l15 = lane & 15, l4 = lane >> 4;
    int qw = q0 + w * 16;          // wave owns 16 q rows
    int swz = l15 & 7;

    bf16x8 qh[2], ql[2];
#pragma unroll
    for (int hf = 0; hf < 2; ++hf) {
        const float* qp = qo + (size_t)(b * SS + qw + l15) * DD + h * 64 + hf * 32 + l4 * 8;
        float4 a = *(const float4*)qp;
        float4 c = *(const float4*)(qp + 4);
        float vv[8] = {a.x, a.y, a.z, a.w, c.x, c.y, c.z, c.w};
        bf16x8 hq, lq;
#pragma unroll
        for (int j = 0; j < 8; ++j) {
            us hh = f2bf(vv[j]);
            hq[j] = (short)hh;
            lq[j] = (short)f2bf(vv[j] - bf2f(hh));
        }
        qh[hf] = hq; ql[hf] = lq;
    }

    f32x4 zero4 = {0.f, 0.f, 0.f, 0.f};
    f32x4 of[4];
#pragma unroll
    for (int j = 0; j < 4; ++j) of[j] = zero4;
    float mrow = -1e30f, lrowp = 0.f;   // per-lane partial sum

    // staging: 512 threads cover one 64x64 array per gll16; row r=tid>>3, granule XOR-swizzled
    int r0 = tid >> 3, sl0 = (tid & 7) ^ (r0 & 7);
    int koff0 = (bh * SS + r0) * 64 + sl0 * 8;
    int voff0 = (bh * 64 + r0) * SS + sl0 * 8;

    int ntiles = qt * 2 + 2;

#define STAGE(buf, tt)                                           \
    do {                                                         \
        int kv_ = (tt) * 64;                                     \
        us* D_ = &L[(buf)][0];                                   \
        int kadd_ = kv_ << 6;                                    \
        gll16(Khg + koff0 + kadd_, D_ + tid * 8);                \
        gll16(Klg + koff0 + kadd_, D_ + 4096 + tid * 8);         \
        gll16(vth + voff0 + kv_, D_ + 8192 + tid * 8);           \
        gll16(vtl + voff0 + kv_, D_ + 12288 + tid * 8);          \
    } while (0)

    STAGE(0, 0);
    STAGE(1, 1);
    int cur = 0;

    for (int t = 0; t < ntiles; ++t) {
        int kv0 = t * 64;
        if (t + 1 < ntiles) { WAITVM(4); } else { WAITVM(0); }
        __builtin_amdgcn_s_barrier();

        if (kv0 <= qw + 15) {
            const us* Lc = &L[cur][0];

            f32x4 sf[4];
#pragma unroll
            for (int i = 0; i < 4; ++i) sf[i] = zero4;
            __builtin_amdgcn_s_setprio(1);
#pragma unroll
            for (int kb = 0; kb < 4; ++kb) {
                int rbase = (kb * 16 + l15) * 64;
#pragma unroll
                for (int hf = 0; hf < 2; ++hf) {
                    int off = rbase + (((hf * 4 + l4) ^ swz) * 8);
                    bf16x8 kh = *(const bf16x8*)(Lc + off);
                    bf16x8 kl = *(const bf16x8*)(Lc + 4096 + off);
                    sf[kb] = __builtin_amdgcn_mfma_f32_16x16x32_bf16(kh, qh[hf], sf[kb], 0, 0, 0);
                    sf[kb] = __builtin_amdgcn_mfma_f32_16x16x32_bf16(kh, ql[hf], sf[kb], 0, 0, 0);
                    sf[kb] = __builtin_amdgcn_mfma_f32_16x16x32_bf16(kl, qh[hf], sf[kb], 0, 0, 0);
                }
            }
            __builtin_amdgcn_s_setprio(0);

            bool diag = (kv0 + 63 > qw);   // wave-uniform
            u32x4 PH[2], PL[2];
            {
                float pv[16];
                if (diag) {
                    int qg = qw + l15;
#pragma unroll
                    for (int kb = 0; kb < 4; ++kb)
#pragma unroll
                        for (int rr = 0; rr < 4; ++rr) {
                            int kvg = kv0 + kb * 16 + l4 * 4 + rr;
                            pv[kb * 4 + rr] = (kvg > qg) ? -1e30f : sf[kb][rr];
                        }
                } else {
#pragma unroll
                    for (int kb = 0; kb < 4; ++kb)
#pragma unroll
                        for (int rr = 0; rr < 4; ++rr)
                            pv[kb * 4 + rr] = sf[kb][rr];
                }
                // max3-shaped reduction tree
                float t0 = fmaxf(fmaxf(pv[0], pv[1]), pv[2]);
                float t1 = fmaxf(fmaxf(pv[3], pv[4]), pv[5]);
                float t2 = fmaxf(fmaxf(pv[6], pv[7]), pv[8]);
                float t3 = fmaxf(fmaxf(pv[9], pv[10]), pv[11]);
                float t4 = fmaxf(fmaxf(pv[12], pv[13]), pv[14]);
                float tmax = fmaxf(fmaxf(fmaxf(t0, t1), fmaxf(t2, t3)), fmaxf(t4, pv[15]));
                tmax = fmaxf(tmax, __shfl_xor(tmax, 16));
                tmax = fmaxf(tmax, __shfl_xor(tmax, 32));
                float mcur = mrow;
                if (!__all(tmax <= mcur + 8.0f)) {   // defer-max: exact (fac==1 when skipped)
                    float mnew = fmaxf(mcur, tmax);
                    float fac = __builtin_amdgcn_exp2f(mcur - mnew);
                    mrow = mnew; mcur = mnew;
                    lrowp *= fac;
                    float fr0 = __shfl(fac, l4 * 4 + 0);
                    float fr1 = __shfl(fac, l4 * 4 + 1);
                    float fr2 = __shfl(fac, l4 * 4 + 2);
                    float fr3 = __shfl(fac, l4 * 4 + 3);
#pragma unroll
                    for (int hb = 0; hb < 4; ++hb) {
                        of[hb][0] *= fr0; of[hb][1] *= fr1;
                        of[hb][2] *= fr2; of[hb][3] *= fr3;
                    }
                }
                float ps = 0.f;
#pragma unroll
                for (int i = 0; i < 16; ++i) {
                    pv[i] = __builtin_amdgcn_exp2f(pv[i] - mcur);
                    ps += pv[i];
                }
                lrowp += ps;                 // per-lane partial; cross-lane at epilogue
#pragma unroll
                for (int ks = 0; ks < 2; ++ks)
#pragma unroll
                    for (int c2 = 0; c2 < 4; ++c2) {
                        float p0 = pv[ks * 8 + c2 * 2], p1 = pv[ks * 8 + c2 * 2 + 1];
                        unsigned u = cvtpk(p0, p1);
                        float h0 = __uint_as_float(u << 16);
                        float h1 = __uint_as_float(u & 0xffff0000u);
                        unsigned ul = cvtpk(p0 - h0, p1 - h1);
                        PH[ks][c2] = u; PL[ks][c2] = ul;
                    }
            }

            __builtin_amdgcn_s_setprio(1);
#pragma unroll
            for (int hb = 0; hb < 4; ++hb) {
                int rbase = (hb * 16 + l15) * 64;
#pragma unroll
                for (int ks = 0; ks < 2; ++ks) {
                    int off = rbase + (((ks * 4 + l4) ^ swz) * 8);
                    bf16x8 vh = *(const bf16x8*)(Lc + 8192 + off);
                    bf16x8 vl = *(const bf16x8*)(Lc + 12288 + off);
                    bf16x8 pa = (bf16x8)PH[ks];
                    bf16x8 pb = (bf16x8)PL[ks];
                    of[hb] = __builtin_amdgcn_mfma_f32_16x16x32_bf16(pa, vh, of[hb], 0, 0, 0);
                    of[hb] = __builtin_amdgcn_mfma_f32_16x16x32_bf16(pa, vl, of[hb], 0, 0, 0);
                    of[hb] = __builtin_amdgcn_mfma_f32_16x16x32_bf16(pb, vh, of[hb], 0, 0, 0);
                }
            }
            __builtin_amdgcn_s_setprio(0);
        }

        __builtin_amdgcn_s_barrier();
        if (t + 2 < ntiles) STAGE(cur, t + 2);
        cur ^= 1;
    }
#undef STAGE

    {
        float lr = lrowp;
        lr += __shfl_xor(lr, 16);
        lr += __shfl_xor(lr, 32);
        float linv = 1.f / lr;
        float f0 = __shfl(linv, l4 * 4 + 0);
        float f1 = __shfl(linv, l4 * 4 + 1);
        float f2 = __shfl(linv, l4 * 4 + 2);
        float f3 = __shfl(linv, l4 * 4 + 3);
        int qgb = qw + l4 * 4;
#pragma unroll
        for (int hb = 0; hb < 4; ++hb) {
            int col = h * 64 + hb * 16 + l15;
            qo[((size_t)(b * SS + qgb + 0)) * DD + col] = of[hb][0] * f0;
            qo[((size_t)(b * SS + qgb + 1)) * DD + col] = of[hb][1] * f1;
            qo[((size_t)(b * SS + qgb + 2)) * DD + col] = of[hb][2] * f2;
            qo[((size_t)(b * SS + qgb + 3)) * DD + col] = of[hb][3] * f3;
        }
    }
}

// ---------------- launcher ----------------

extern "C" void kernel_launch(void* const* d_in, const int* in_sizes, int n_in,
                              void* d_out, int out_size, void* d_ws, size_t ws_size,
                              hipStream_t stream) {
    const float* hidden  = (const float*)d_in[0];
    const float* W_attn  = (const float*)d_in[2];
    const float* b_attn  = (const float*)d_in[3];
    const float* lA_attn = (const float*)d_in[4];
    const float* lB_attn = (const float*)d_in[5];
    const float* W_proj  = (const float*)d_in[6];
    const float* b_proj  = (const float*)d_in[7];
    const float* lA_proj = (const float*)d_in[8];
    const float* lB_proj = (const float*)d_in[9];
    float* out = (float*)d_out;

    char* ws = (char*)d_ws;
    unsigned* s1 = (unsigned*)(ws);
    unsigned* s2 = (unsigned*)(ws + 4096);
    us* xq  = (us*)(ws + 8192);                              // 17,825,792 B (8192x1088x2)
    us* vth = xq;                                            // overlay (phase B: xq dead)
    us* wh1 = (us*)(ws + 8192 + 17825792);                   // 6,684,672
    us* wl1 = (us*)(ws + 8192 + 17825792 + 6684672);         // 6,684,672
    us* wh2 = (us*)(ws + 8192 + 17825792 + 2 * 6684672);     // 2,228,224
    us* wl2 = (us*)(ws + 8192 + 17825792 + 2 * 6684672 + 2228224);
    char* pbase = ws + 8192 + 17825792 + 2 * 6684672 + 2 * 2228224;
    float* qbuf = (float*)pbase;                             // 33,554,432 (q plane; attn out in-place)
    float* vbuf = (float*)(pbase + 33554432);                // 33,554,432 (v plane, dead after transpose)
    us* Khg = (us*)(pbase + 2 * (size_t)33554432);           // 16,777,216
    us* Klg = (us*)(pbase + 2 * (size_t)33554432 + 16777216);
    us* vtl = (us*)(pbase + 2 * (size_t)33554432 + 2 * (size_t)16777216);  // 16,777,216

    k_zero<<<8, 256, 0, stream>>>(s1, 2048);

    // ---- qkv projection ----
    k_colmax<<<dim3(4, 64), 256, 0, stream>>>(hidden, s1);
    k_quant_lora<<<MTOT, 256, 0, stream>>>(hidden, s1, lA_attn, xq);
    k_quant_w<<<3072, 256, 0, stream>>>(W_attn, lB_attn, b_attn, s1, wh1, wl1, 3072);
    k_gemm<1><<<dim3(32, 24), 512, 0, stream>>>(xq, wh1, wl1, qbuf, DQKV, Khg, Klg, vbuf);

    // ---- attention (output in-place into qbuf) ----
    k_transpose_v<<<dim3(32, 64), 256, 0, stream>>>(vbuf, vth, vtl);
    k_attn<<<dim3(64, 16), 512, 0, stream>>>(qbuf, Khg, Klg, vth, vtl);

    // ---- output projection ----
    k_colmax<<<dim3(4, 64), 256, 0, stream>>>(qbuf, s2);
    k_quant_lora<<<MTOT, 256, 0, stream>>>(qbuf, s2, lA_proj, xq);
    k_quant_w<<<1024, 256, 0, stream>>>(W_proj, lB_proj, b_proj, s2, wh2, wl2, 1024);
    k_gemm<0><<<dim3(32, 8), 512, 0, stream>>>(xq, wh2, wl2, out, DD, nullptr, nullptr, nullptr);
}

// Round 14
// 455.728 us; speedup vs baseline: 1.0822x; 1.0822x over previous
//
#include <hip/hip_runtime.h>

#define SS 2048
#define DD 1024
#define DQKV 3072
#define KP 1088            // 1024 + 16 lora-hi + 16 lora-lo + 1 bias + 31 pad
#define NT64 17            // K-tiles of 64
#define MTOT 8192
#define QKSZ ((size_t)MTOT * DD)   // floats per q/k/v plane
#define SCL 0.18033688011112042f   /* 0.125 * log2(e), folded into K plane */

typedef unsigned short us;
typedef __attribute__((ext_vector_type(8))) short bf16x8;
typedef __attribute__((ext_vector_type(4))) float f32x4;
typedef __attribute__((ext_vector_type(4))) unsigned u32x4;

#define WAITVM(N) asm volatile("s_waitcnt vmcnt(" #N ")" ::: "memory")
#define WAITLGKM0 asm volatile("s_waitcnt lgkmcnt(0)" ::: "memory")

__device__ __forceinline__ us f2bf(float f) {
    unsigned u = __float_as_uint(f);
    return (us)((u + 0x7fffu + ((u >> 16) & 1u)) >> 16);
}
__device__ __forceinline__ float bf2f(us h) { return __uint_as_float(((unsigned)h) << 16); }
__device__ __forceinline__ void split2(float q, us& h, us& l) {
    h = f2bf(q); l = f2bf(q - bf2f(h));
}
__device__ __forceinline__ unsigned cvtpk(float lo, float hi) {
    unsigned r;
    asm("v_cvt_pk_bf16_f32 %0, %1, %2" : "=v"(r) : "v"(lo), "v"(hi));
    return r;
}

// exact log-domain fake quant level: e = round(log2(clip(|x|/s, 2^-255, 1)))
// f32 candidate + exact double-MUL boundary correction (bit-identical to double-divide:
// r >= 2^(k-0.5)  <=>  ax^2 >= s^2 * 2^(2k-1); ax^2, s^2, ldexp exact in double)
__device__ __forceinline__ int logq_e(float ax, float s) {
    int e = 0;
    if (ax < s) {
        int ex;
        float m = frexpf(ax / s, &ex);
        int k = (m >= 0.70710678f) ? ex : ex - 1;   // f32 candidate (within +-1 of exact)
        double ax2 = (double)ax * (double)ax;       // exact
        double s2 = (double)s * (double)s;          // exact
        if (ax2 >= ldexp(s2, 2 * k + 1)) k += 1;
        else if (ax2 < ldexp(s2, 2 * k - 1)) k -= 1;
        if (k > 0) k = 0;
        e = (k < -255) ? -255 : k;
    }
    return e;
}
__device__ __forceinline__ float logq_exact(float x, float s) {
    float ax = fabsf(x);
    if (ax == 0.f) return copysignf(0.f, x);
    return copysignf(ldexpf(s, logq_e(ax, s)), x);
}

__device__ __forceinline__ void gll16(const void* g, void* l) {
    __builtin_amdgcn_global_load_lds(
        (const __attribute__((address_space(1))) void*)g,
        (__attribute__((address_space(3))) void*)l, 16, 0, 0);
}

// ---------------- scales / quant / lora prep ----------------

__global__ void k_colmax(const float* __restrict__ x, unsigned* __restrict__ smax) {
    int c = blockIdx.x * 256 + threadIdx.x;
    int r0 = blockIdx.y * 128;
    float m = 0.f;
    for (int r = 0; r < 128; ++r) m = fmaxf(m, fabsf(x[(size_t)(r0 + r) * DD + c]));
    atomicMax(smax + c, __float_as_uint(m));
}

// fused: quantize row (exact bf16 rep Ah) + lora cols + bias/pad; one pass over x
__global__ __launch_bounds__(256) void k_quant_lora(const float* __restrict__ x,
                                                    const unsigned* __restrict__ smax,
                                                    const float* __restrict__ lA,
                                                    us* __restrict__ xq) {
    __shared__ float red[4][16];
    int m = blockIdx.x, tx = threadIdx.x;
    int lane = tx & 63, w = tx >> 6;
    float4 xv = ((const float4*)(x + (size_t)m * DD))[tx];
    int c = tx * 4;
    float vv[4] = {xv.x, xv.y, xv.z, xv.w};
    ushort4 qh;
    us* ph = (us*)&qh;
#pragma unroll
    for (int j = 0; j < 4; ++j) {
        float s = fmaxf(__uint_as_float(smax[c + j]), 1e-8f);
        float sh = bf2f(f2bf(s));
        float ax = fabsf(vv[j]);
        if (ax == 0.f) ph[j] = (us)((__float_as_uint(vv[j]) >> 16) & 0x8000u);
        else ph[j] = f2bf(copysignf(ldexpf(sh, logq_e(ax, s)), vv[j]));
    }
    *(ushort4*)(xq + (size_t)m * KP + c) = qh;
    float acc[16];
#pragma unroll
    for (int r = 0; r < 16; ++r) acc[r] = 0.f;
#pragma unroll
    for (int j = 0; j < 4; ++j) {
        float xs = vv[j];
        const float4* lr = (const float4*)(lA + (size_t)(c + j) * 16);
        float4 a0 = lr[0], a1 = lr[1], a2 = lr[2], a3 = lr[3];
        acc[0] += xs * a0.x; acc[1] += xs * a0.y; acc[2] += xs * a0.z; acc[3] += xs * a0.w;
        acc[4] += xs * a1.x; acc[5] += xs * a1.y; acc[6] += xs * a1.z; acc[7] += xs * a1.w;
        acc[8] += xs * a2.x; acc[9] += xs * a2.y; acc[10] += xs * a2.z; acc[11] += xs * a2.w;
        acc[12] += xs * a3.x; acc[13] += xs * a3.y; acc[14] += xs * a3.z; acc[15] += xs * a3.w;
    }
#pragma unroll
    for (int msk = 1; msk < 64; msk <<= 1)
#pragma unroll
        for (int r = 0; r < 16; ++r) acc[r] += __shfl_xor(acc[r], msk);
    if (lane == 0)
#pragma unroll
        for (int r = 0; r < 16; ++r) red[w][r] = acc[r];
    __syncthreads();
    if (tx < 16) {
        float v = 2.0f * (red[0][tx] + red[1][tx] + red[2][tx] + red[3][tx]);
        us h, l; split2(v, h, l);
        xq[(size_t)m * KP + 1024 + tx] = h;
        xq[(size_t)m * KP + 1040 + tx] = l;
    } else if (tx == 16) {
        xq[(size_t)m * KP + 1056] = 0x3F80;   // bias col = 1.0
    } else if (tx < 48) {
        xq[(size_t)m * KP + 1040 + tx] = 0;   // pads 1057..1087
    }
}

// weight quant + fold activation-scale residual: W' = Wq*(1+rho_c); split hi/lo.
__global__ __launch_bounds__(256) void k_quant_w(const float* __restrict__ W, const float* __restrict__ lB,
                                                 const float* __restrict__ bias,
                                                 const unsigned* __restrict__ smax,
                                                 us* __restrict__ wh, us* __restrict__ wl, int Nn) {
    __shared__ float red[4];
    int n = blockIdx.x, tx = threadIdx.x;
    int lane = tx & 63, w = tx >> 6;
    float4 wv = ((const float4*)(W + (size_t)n * DD))[tx];
    float m4 = fmaxf(fmaxf(fabsf(wv.x), fabsf(wv.y)), fmaxf(fabsf(wv.z), fabsf(wv.w)));
#pragma unroll
    for (int msk = 1; msk < 64; msk <<= 1) m4 = fmaxf(m4, __shfl_xor(m4, msk));
    if (lane == 0) red[w] = m4;
    __syncthreads();
    float t = fmaxf(fmaxf(fmaxf(red[0], red[1]), fmaxf(red[2], red[3])), 1e-8f);
    float vv[4] = {wv.x, wv.y, wv.z, wv.w};
    int c = tx * 4;
    ushort4 qh, ql;
    us* ph = (us*)&qh; us* pl = (us*)&ql;
#pragma unroll
    for (int j = 0; j < 4; ++j) {
        float s = fmaxf(__uint_as_float(smax[c + j]), 1e-8f);
        float sh = bf2f(f2bf(s));
        float rho = (s - sh) / sh;
        float q = logq_exact(vv[j], t);
        float wp = q + q * rho;
        split2(wp, ph[j], pl[j]);
    }
    *(ushort4*)(wh + (size_t)n * KP + c) = qh;
    *(ushort4*)(wl + (size_t)n * KP + c) = ql;
    if (tx < 64) {
        us h = 0, l = 0;
        if (tx < 32) { int r = tx & 15; split2(lB[(size_t)r * Nn + n], h, l); }
        else if (tx == 32) split2(bias[n], h, l);
        wh[(size_t)n * KP + 1024 + tx] = h;
        wl[(size_t)n * KP + 1024 + tx] = l;
    }
}

// ---------------- GEMM: C = Ah @ (W'h + W'l)^T, 2 MFMA passes ----------------
// 8-wave (512t) BM=256 BN=128 BK=64; 2 sub-phases per K-tile; counted vmcnt(8);
// GSTAGE(t+2) overlapped with ksub1 MFMA; XOR8-granule swizzle (g ^= row&7) both-sides.
// bn = blockIdx.x (XCD = bn%8 -> B panels L2-resident), bm = blockIdx.y.
// MODE 0: linear f32 C[M][Nn].  MODE 1: qkv epilogue — q f32, v f32, k*SCL split bf16 [bh][s][64].

template <int MODE>
__global__ __launch_bounds__(512, 2) void k_gemm(const us* __restrict__ Aq_,
                                                 const us* __restrict__ Bh_, const us* __restrict__ Bl_,
                                                 float* __restrict__ C, int Nn,
                                                 us* __restrict__ Khg, us* __restrict__ Klg,
                                                 float* __restrict__ vbuf) {
    __shared__ us LA[2][16384];    // A 256x64 bf16 per buf (64KB total)
    __shared__ us LBh[2][8192];    // Bh 128x64 (32KB)
    __shared__ us LBl[2][8192];    // Bl 128x64 (32KB)
    int tid = threadIdx.x;
    int bn = blockIdx.x, bm = blockIdx.y;
    int lane = tid & 63, w = tid >> 6;
    int wm = w >> 2, wn = w & 3;             // 2 x 4 wave grid; per-wave out 128x32
    int l15 = lane & 15, l4 = lane >> 4;
    int srow = tid >> 3;
    int gsrc = ((tid & 7) ^ (srow & 7)) * 8;
    const us* aP  = Aq_ + (size_t)(bm * 256 + srow) * KP + gsrc;
    const us* bhP = Bh_ + (size_t)(bn * 128 + srow) * KP + gsrc;
    const us* blP = Bl_ + (size_t)(bn * 128 + srow) * KP + gsrc;
    f32x4 zero4 = {0.f, 0.f, 0.f, 0.f};
    f32x4 acc[8][2];
#pragma unroll
    for (int i = 0; i < 8; ++i) { acc[i][0] = zero4; acc[i][1] = zero4; }

#define GSTAGE(buf, kt)                                               \
    do {                                                              \
        int k0_ = (kt) * 64;                                          \
        gll16(aP + k0_,                    &LA[(buf)][0]     + tid * 8); \
        gll16(aP + (size_t)64  * KP + k0_, &LA[(buf)][4096]  + tid * 8); \
        gll16(aP + (size_t)128 * KP + k0_, &LA[(buf)][8192]  + tid * 8); \
        gll16(aP + (size_t)192 * KP + k0_, &LA[(buf)][12288] + tid * 8); \
        gll16(bhP + k0_,                   &LBh[(buf)][0]    + tid * 8); \
        gll16(bhP + (size_t)64 * KP + k0_, &LBh[(buf)][4096] + tid * 8); \
        gll16(blP + k0_,                   &LBl[(buf)][0]    + tid * 8); \
        gll16(blP + (size_t)64 * KP + k0_, &LBl[(buf)][4096] + tid * 8); \
    } while (0)

    GSTAGE(0, 0);
    GSTAGE(1, 1);
    WAITVM(8);
    __builtin_amdgcn_s_barrier();
    __builtin_amdgcn_sched_barrier(0);

    int gsw0 = ((l4)     ^ (l15 & 7)) * 8;   // ksub0 granule (swizzled), elements
    int gsw1 = ((4 + l4) ^ (l15 & 7)) * 8;   // ksub1
    int cur = 0;
    for (int kt = 0; kt < NT64; ++kt) {
        const us* A0  = &LA[cur][0];
        const us* Bh0 = &LBh[cur][0];
        const us* Bl0 = &LBl[cur][0];
        // ---- sub-phase 0 ----
        bf16x8 a0[8], b0h[2], b0l[2];
#pragma unroll
        for (int i = 0; i < 8; ++i)
            a0[i] = *(const bf16x8*)(A0 + (wm * 128 + i * 16 + l15) * 64 + gsw0);
#pragma unroll
        for (int i = 0; i < 2; ++i) {
            b0h[i] = *(const bf16x8*)(Bh0 + (wn * 32 + i * 16 + l15) * 64 + gsw0);
            b0l[i] = *(const bf16x8*)(Bl0 + (wn * 32 + i * 16 + l15) * 64 + gsw0);
        }
        __builtin_amdgcn_s_setprio(1);
#pragma unroll
        for (int mi = 0; mi < 8; ++mi)
#pragma unroll
            for (int ni = 0; ni < 2; ++ni) {
                acc[mi][ni] = __builtin_amdgcn_mfma_f32_16x16x32_bf16(a0[mi], b0h[ni], acc[mi][ni], 0, 0, 0);
                acc[mi][ni] = __builtin_amdgcn_mfma_f32_16x16x32_bf16(a0[mi], b0l[ni], acc[mi][ni], 0, 0, 0);
            }
        __builtin_amdgcn_s_setprio(0);
        // ---- sub-phase 1 reads ----
        bf16x8 a1[8], b1h[2], b1l[2];
#pragma unroll
        for (int i = 0; i < 8; ++i)
            a1[i] = *(const bf16x8*)(A0 + (wm * 128 + i * 16 + l15) * 64 + gsw1);
#pragma unroll
        for (int i = 0; i < 2; ++i) {
            b1h[i] = *(const bf16x8*)(Bh0 + (wn * 32 + i * 16 + l15) * 64 + gsw1);
            b1l[i] = *(const bf16x8*)(Bl0 + (wn * 32 + i * 16 + l15) * 64 + gsw1);
        }
        WAITLGKM0;                          // this wave done reading buf[cur]
        __builtin_amdgcn_sched_barrier(0);
        __builtin_amdgcn_s_barrier();       // all waves done reading buf[cur]
        __builtin_amdgcn_sched_barrier(0);
        if (kt + 2 < NT64) GSTAGE(cur, kt + 2);   // restage freed buffer; overlaps MFMA below
        __builtin_amdgcn_s_setprio(1);
#pragma unroll
        for (int mi = 0; mi < 8; ++mi)
#pragma unroll
            for (int ni = 0; ni < 2; ++ni) {
                acc[mi][ni] = __builtin_amdgcn_mfma_f32_16x16x32_bf16(a1[mi], b1h[ni], acc[mi][ni], 0, 0, 0);
                acc[mi][ni] = __builtin_amdgcn_mfma_f32_16x16x32_bf16(a1[mi], b1l[ni], acc[mi][ni], 0, 0, 0);
            }
        __builtin_amdgcn_s_setprio(0);
        if (kt + 2 < NT64) { WAITVM(8); } else { WAITVM(0); }   // tile kt+1 landed
        __builtin_amdgcn_s_barrier();
        __builtin_amdgcn_sched_barrier(0);
        cur ^= 1;
    }
#undef GSTAGE

    int plane = bn >> 3;   // MODE 1 only; block-uniform
#pragma unroll
    for (int mi = 0; mi < 8; ++mi) {
#pragma unroll
        for (int ni = 0; ni < 2; ++ni) {
            int ncol = bn * 128 + wn * 32 + ni * 16 + l15;
            size_t mbase = (size_t)bm * 256 + wm * 128 + mi * 16 + l4 * 4;
#pragma unroll
            for (int rr = 0; rr < 4; ++rr) {
                float v = acc[mi][ni][rr];
                size_t m = mbase + rr;
                if (MODE == 0) {
                    C[m * (size_t)Nn + ncol] = v;
                } else {
                    int cc = ncol & 1023;
                    if (plane == 0) {
                        C[m * DD + cc] = v;
                    } else if (plane == 2) {
                        vbuf[m * DD + cc] = v;
                    } else {
                        us hh, ll; split2(v * SCL, hh, ll);   // fold softmax scale into K
                        size_t d = ((size_t)((m >> 11) * 16 + (cc >> 6)) * SS + (m & 2047)) * 64 + (cc & 63);
                        Khg[d] = hh; Klg[d] = ll;
                    }
                }
            }
        }
    }
}

// ---------------- V transpose+split: vbuf f32 -> vth/vtl [bh][hd][s-permuted] bf16 ----------------

__global__ __launch_bounds__(256) void k_transpose_v(const float* __restrict__ vbuf,
                                                     us* __restrict__ vth, us* __restrict__ vtl) {
    __shared__ us th[64][72], tl[64][72];
    int st = blockIdx.x, bh = blockIdx.y;
    int bb = bh >> 4, h = bh & 15;
    int s0 = st * 64, tid = threadIdx.x;
    int sl = tid >> 2, c0 = (tid & 3) * 16;
    const float* src = vbuf + (size_t)(bb * SS + s0 + sl) * DD + h * 64 + c0;
#pragma unroll
    for (int j4 = 0; j4 < 4; ++j4) {
        float4 v = *(const float4*)(src + j4 * 4);
        float vv[4] = {v.x, v.y, v.z, v.w};
#pragma unroll
        for (int j = 0; j < 4; ++j) {
            us hh, ll; split2(vv[j], hh, ll);
            th[c0 + j4 * 4 + j][sl] = hh;
            tl[c0 + j4 * 4 + j][sl] = ll;
        }
    }
    __syncthreads();
#pragma unroll
    for (int p = 0; p < 2; ++p) {
        int gidx = p * 256 + tid;
        int hd = gidx >> 3, g = gidx & 7;
        int base = (g >> 2) * 32 + (g & 3) * 4;
        ushort4 a, b2, c, d2;
        a.x = th[hd][base];      a.y = th[hd][base + 1];  a.z = th[hd][base + 2];  a.w = th[hd][base + 3];
        b2.x = th[hd][base + 16]; b2.y = th[hd][base + 17]; b2.z = th[hd][base + 18]; b2.w = th[hd][base + 19];
        c.x = tl[hd][base];      c.y = tl[hd][base + 1];  c.z = tl[hd][base + 2];  c.w = tl[hd][base + 3];
        d2.x = tl[hd][base + 16]; d2.y = tl[hd][base + 17]; d2.z = tl[hd][base + 18]; d2.w = tl[hd][base + 19];
        size_t dof = ((size_t)bh * 64 + hd) * SS + s0 + g * 8;
        *(ushort4*)(vth + dof) = a;  *(ushort4*)(vth + dof + 4) = b2;
        *(ushort4*)(vtl + dof) = c;  *(ushort4*)(vtl + dof + 4) = d2;
    }
}

// ---------------- causal flash attention; 8 waves x 16 q-rows (128/block); counted-vmcnt; defer-max ----
// output written IN-PLACE into the q plane; K plane pre-scaled by SCL.
// grid (64 bh, 16 y), qt = 15-y (heavy first); 1024 blocks = 2 dispatch rounds -> dynamic balance.

__global__ __launch_bounds__(512, 2) void k_attn(float* qo,
                                                 const us* __restrict__ Khg, const us* __restrict__ Klg,
                                                 const us* __restrict__ vth, const us* __restrict__ vtl) {
    __shared__ us L[2][16384];  // per buf: [0]=Kh [4096]=Kl [8192]=Vh [12288]=Vl, 64x64 bf16, XOR-8 swz
    int bh = blockIdx.x;
    int qt = (int)(gridDim.y - 1) - blockIdx.y;   // heavy q-tiles first
    int b = bh >> 4, h = bh & 15;
    int q0 = qt * 128;
    int tid = threadIdx.x, w = tid >> 6, lane = tid & 63;
    int l15 = lane & 15, l4 = lane >> 4;
    int qw = q0 + w * 16;          // wave owns 16 q rows
    int swz = l15 & 7;

    bf16x8 qh[2], ql[2];
#pragma unroll
    for (int hf = 0; hf < 2; ++hf) {
        const float* qp = qo + (size_t)(b * SS + qw + l15) * DD + h * 64 + hf * 32 + l4 * 8;
        float4 a = *(const float4*)qp;
        float4 c = *(const float4*)(qp + 4);
        float vv[8] = {a.x, a.y, a.z, a.w, c.x, c.y, c.z, c.w};
        bf16x8 hq, lq;
#pragma unroll
        for (int j = 0; j < 8; ++j) {
            us hh = f2bf(vv[j]);
            hq[j] = (short)hh;
            lq[j] = (short)f2bf(vv[j] - bf2f(hh));
        }
        qh[hf] = hq; ql[hf] = lq;
    }

    f32x4 zero4 = {0.f, 0.f, 0.f, 0.f};
    f32x4 of[4];
#pragma unroll
    for (int j = 0; j < 4; ++j) of[j] = zero4;
    float mrow = -1e30f, lrowp = 0.f;   // per-lane partial sum

    int r0 = tid >> 3, sl0 = (tid & 7) ^ (r0 & 7);
    int koff0 = (bh * SS + r0) * 64 + sl0 * 8;
    int voff0 = (bh * 64 + r0) * SS + sl0 * 8;

    int ntiles = qt * 2 + 2;

#define STAGE(buf, tt)                                           \
    do {                                                         \
        int kv_ = (tt) * 64;                                     \
        us* D_ = &L[(buf)][0];                                   \
        int kadd_ = kv_ << 6;                                    \
        gll16(Khg + koff0 + kadd_, D_ + tid * 8);                \
        gll16(Klg + koff0 + kadd_, D_ + 4096 + tid * 8);         \
        gll16(vth + voff0 + kv_, D_ + 8192 + tid * 8);           \
        gll16(vtl + voff0 + kv_, D_ + 12288 + tid * 8);          \
    } while (0)

    STAGE(0, 0);
    STAGE(1, 1);
    int cur = 0;

    for (int t = 0; t < ntiles; ++t) {
        int kv0 = t * 64;
        if (t + 1 < ntiles) { WAITVM(4); } else { WAITVM(0); }
        __builtin_amdgcn_s_barrier();

        if (kv0 <= qw + 15) {
            const us* Lc = &L[cur][0];

            f32x4 sf[4];
#pragma unroll
            for (int i = 0; i < 4; ++i) sf[i] = zero4;
            __builtin_amdgcn_s_setprio(1);
#pragma unroll
            for (int kb = 0; kb < 4; ++kb) {
                int rbase = (kb * 16 + l15) * 64;
#pragma unroll
                for (int hf = 0; hf < 2; ++hf) {
                    int off = rbase + (((hf * 4 + l4) ^ swz) * 8);
                    bf16x8 kh = *(const bf16x8*)(Lc + off);
                    bf16x8 kl = *(const bf16x8*)(Lc + 4096 + off);
                    sf[kb] = __builtin_amdgcn_mfma_f32_16x16x32_bf16(kh, qh[hf], sf[kb], 0, 0, 0);
                    sf[kb] = __builtin_amdgcn_mfma_f32_16x16x32_bf16(kh, ql[hf], sf[kb], 0, 0, 0);
                    sf[kb] = __builtin_amdgcn_mfma_f32_16x16x32_bf16(kl, qh[hf], sf[kb], 0, 0, 0);
                }
            }
            __builtin_amdgcn_s_setprio(0);

            bool diag = (kv0 + 63 > qw);   // wave-uniform
            u32x4 PH[2], PL[2];
            {
                float pv[16];
                if (diag) {
                    int qg = qw + l15;
#pragma unroll
                    for (int kb = 0; kb < 4; ++kb)
#pragma unroll
                        for (int rr = 0; rr < 4; ++rr) {
                            int kvg = kv0 + kb * 16 + l4 * 4 + rr;
                            pv[kb * 4 + rr] = (kvg > qg) ? -1e30f : sf[kb][rr];
                        }
                } else {
#pragma unroll
                    for (int kb = 0; kb < 4; ++kb)
#pragma unroll
                        for (int rr = 0; rr < 4; ++rr)
                            pv[kb * 4 + rr] = sf[kb][rr];
                }
                float t0 = fmaxf(fmaxf(pv[0], pv[1]), pv[2]);
                float t1 = fmaxf(fmaxf(pv[3], pv[4]), pv[5]);
                float t2 = fmaxf(fmaxf(pv[6], pv[7]), pv[8]);
                float t3 = fmaxf(fmaxf(pv[9], pv[10]), pv[11]);
                float t4 = fmaxf(fmaxf(pv[12], pv[13]), pv[14]);
                float tmax = fmaxf(fmaxf(fmaxf(t0, t1), fmaxf(t2, t3)), fmaxf(t4, pv[15]));
                tmax = fmaxf(tmax, __shfl_xor(tmax, 16));
                tmax = fmaxf(tmax, __shfl_xor(tmax, 32));
                float mcur = mrow;
                if (!__all(tmax <= mcur + 8.0f)) {   // defer-max: exact (fac==1 when skipped)
                    float mnew = fmaxf(mcur, tmax);
                    float fac = __builtin_amdgcn_exp2f(mcur - mnew);
                    mrow = mnew; mcur = mnew;
                    lrowp *= fac;
                    float fr0 = __shfl(fac, l4 * 4 + 0);
                    float fr1 = __shfl(fac, l4 * 4 + 1);
                    float fr2 = __shfl(fac, l4 * 4 + 2);
                    float fr3 = __shfl(fac, l4 * 4 + 3);
#pragma unroll
                    for (int hb = 0; hb < 4; ++hb) {
                        of[hb][0] *= fr0; of[hb][1] *= fr1;
                        of[hb][2] *= fr2; of[hb][3] *= fr3;
                    }
                }
                float ps = 0.f;
#pragma unroll
                for (int i = 0; i < 16; ++i) {
                    pv[i] = __builtin_amdgcn_exp2f(pv[i] - mcur);
                    ps += pv[i];
                }
                lrowp += ps;                 // per-lane partial; cross-lane at epilogue
#pragma unroll
                for (int ks = 0; ks < 2; ++ks)
#pragma unroll
                    for (int c2 = 0; c2 < 4; ++c2) {
                        float p0 = pv[ks * 8 + c2 * 2], p1 = pv[ks * 8 + c2 * 2 + 1];
                        unsigned u = cvtpk(p0, p1);
                        float h0 = __uint_as_float(u << 16);
                        float h1 = __uint_as_float(u & 0xffff0000u);
                        unsigned ul = cvtpk(p0 - h0, p1 - h1);
                        PH[ks][c2] = u; PL[ks][c2] = ul;
                    }
            }

            __builtin_amdgcn_s_setprio(1);
#pragma unroll
            for (int hb = 0; hb < 4; ++hb) {
                int rbase = (hb * 16 + l15) * 64;
#pragma unroll
                for (int ks = 0; ks < 2; ++ks) {
                    int off = rbase + (((ks * 4 + l4) ^ swz) * 8);
                    bf16x8 vh = *(const bf16x8*)(Lc + 8192 + off);
                    bf16x8 vl = *(const bf16x8*)(Lc + 12288 + off);
                    bf16x8 pa = (bf16x8)PH[ks];
                    bf16x8 pb = (bf16x8)PL[ks];
                    of[hb] = __builtin_amdgcn_mfma_f32_16x16x32_bf16(pa, vh, of[hb], 0, 0, 0);
                    of[hb] = __builtin_amdgcn_mfma_f32_16x16x32_bf16(pa, vl, of[hb], 0, 0, 0);
                    of[hb] = __builtin_amdgcn_mfma_f32_16x16x32_bf16(pb, vh, of[hb], 0, 0, 0);
                }
            }
            __builtin_amdgcn_s_setprio(0);
        }

        __builtin_amdgcn_s_barrier();
        if (t + 2 < ntiles) STAGE(cur, t + 2);
        cur ^= 1;
    }
#undef STAGE

    {
        float lr = lrowp;
        lr += __shfl_xor(lr, 16);
        lr += __shfl_xor(lr, 32);
        float linv = 1.f / lr;
        float f0 = __shfl(linv, l4 * 4 + 0);
        float f1 = __shfl(linv, l4 * 4 + 1);
        float f2 = __shfl(linv, l4 * 4 + 2);
        float f3 = __shfl(linv, l4 * 4 + 3);
        int qgb = qw + l4 * 4;
#pragma unroll
        for (int hb = 0; hb < 4; ++hb) {
            int col = h * 64 + hb * 16 + l15;
            qo[((size_t)(b * SS + qgb + 0)) * DD + col] = of[hb][0] * f0;
            qo[((size_t)(b * SS + qgb + 1)) * DD + col] = of[hb][1] * f1;
            qo[((size_t)(b * SS + qgb + 2)) * DD + col] = of[hb][2] * f2;
            qo[((size_t)(b * SS + qgb + 3)) * DD + col] = of[hb][3] * f3;
        }
    }
}

// ---------------- launcher ----------------

extern "C" void kernel_launch(void* const* d_in, const int* in_sizes, int n_in,
                              void* d_out, int out_size, void* d_ws, size_t ws_size,
                              hipStream_t stream) {
    const float* hidden  = (const float*)d_in[0];
    const float* W_attn  = (const float*)d_in[2];
    const float* b_attn  = (const float*)d_in[3];
    const float* lA_attn = (const float*)d_in[4];
    const float* lB_attn = (const float*)d_in[5];
    const float* W_proj  = (const float*)d_in[6];
    const float* b_proj  = (const float*)d_in[7];
    const float* lA_proj = (const float*)d_in[8];
    const float* lB_proj = (const float*)d_in[9];
    float* out = (float*)d_out;

    char* ws = (char*)d_ws;
    unsigned* s1 = (unsigned*)(ws);
    unsigned* s2 = (unsigned*)(ws + 4096);
    us* xq  = (us*)(ws + 8192);                              // 17,825,792 B (8192x1088x2)
    us* vth = xq;                                            // overlay (phase B: xq dead)
    us* wh1 = (us*)(ws + 8192 + 17825792);                   // 6,684,672
    us* wl1 = (us*)(ws + 8192 + 17825792 + 6684672);         // 6,684,672
    us* wh2 = (us*)(ws + 8192 + 17825792 + 2 * 6684672);     // 2,228,224
    us* wl2 = (us*)(ws + 8192 + 17825792 + 2 * 6684672 + 2228224);
    char* pbase = ws + 8192 + 17825792 + 2 * 6684672 + 2 * 2228224;
    float* qbuf = (float*)pbase;                             // 33,554,432 (q plane; attn out in-place)
    float* vbuf = (float*)(pbase + 33554432);                // 33,554,432 (v plane, dead after transpose)
    us* Khg = (us*)(pbase + 2 * (size_t)33554432);           // 16,777,216
    us* Klg = (us*)(pbase + 2 * (size_t)33554432 + 16777216);
    us* vtl = (us*)(pbase + 2 * (size_t)33554432 + 2 * (size_t)16777216);  // 16,777,216

    hipMemsetAsync(ws, 0, 8192, stream);   // zero s1 + s2

    // ---- qkv projection ----
    k_colmax<<<dim3(4, 64), 256, 0, stream>>>(hidden, s1);
    k_quant_lora<<<MTOT, 256, 0, stream>>>(hidden, s1, lA_attn, xq);
    k_quant_w<<<3072, 256, 0, stream>>>(W_attn, lB_attn, b_attn, s1, wh1, wl1, 3072);
    k_gemm<1><<<dim3(24, 32), 512, 0, stream>>>(xq, wh1, wl1, qbuf, DQKV, Khg, Klg, vbuf);

    // ---- attention (output in-place into qbuf) ----
    k_transpose_v<<<dim3(32, 64), 256, 0, stream>>>(vbuf, vth, vtl);
    k_attn<<<dim3(64, 16), 512, 0, stream>>>(qbuf, Khg, Klg, vth, vtl);

    // ---- output projection ----
    k_colmax<<<dim3(4, 64), 256, 0, stream>>>(qbuf, s2);
    k_quant_lora<<<MTOT, 256, 0, stream>>>(qbuf, s2, lA_proj, xq);
    k_quant_w<<<1024, 256, 0, stream>>>(W_proj, lB_proj, b_proj, s2, wh2, wl2, 1024);
    k_gemm<0><<<dim3(8, 32), 512, 0, stream>>>(xq, wh2, wl2, out, DD, nullptr, nullptr, nullptr);
}

// Round 15
// 439.424 us; speedup vs baseline: 1.1224x; 1.0371x over previous
//
#include <hip/hip_runtime.h>

#define SS 2048
#define DD 1024
#define DQKV 3072
#define KP 1088            // 1024 + 16 lora-hi + 16 lora-lo + 1 bias + 31 pad
#define NT64 17            // K-tiles of 64
#define MTOT 8192
#define QKSZ ((size_t)MTOT * DD)   // floats per q/k/v plane
#define SCL 0.18033688011112042f   /* 0.125 * log2(e), folded into K plane */

typedef unsigned short us;
typedef __attribute__((ext_vector_type(8))) short bf16x8;
typedef __attribute__((ext_vector_type(4))) float f32x4;
typedef __attribute__((ext_vector_type(4))) unsigned u32x4;

#define WAITVM(N) asm volatile("s_waitcnt vmcnt(" #N ")" ::: "memory")
#define WAITLGKM0 asm volatile("s_waitcnt lgkmcnt(0)" ::: "memory")

__device__ __forceinline__ us f2bf(float f) {
    unsigned u = __float_as_uint(f);
    return (us)((u + 0x7fffu + ((u >> 16) & 1u)) >> 16);
}
__device__ __forceinline__ float bf2f(us h) { return __uint_as_float(((unsigned)h) << 16); }
__device__ __forceinline__ void split2(float q, us& h, us& l) {
    h = f2bf(q); l = f2bf(q - bf2f(h));
}
__device__ __forceinline__ unsigned cvtpk(float lo, float hi) {
    unsigned r;
    asm("v_cvt_pk_bf16_f32 %0, %1, %2" : "=v"(r) : "v"(lo), "v"(hi));
    return r;
}

// exact log-domain fake quant level: e = round(log2(clip(|x|/s, 2^-255, 1)))
// f32 candidate + exact double-MUL boundary correction (bit-identical to double-divide:
// r >= 2^(k-0.5)  <=>  ax^2 >= s^2 * 2^(2k-1); ax^2, s^2, ldexp exact in double)
__device__ __forceinline__ int logq_e(float ax, float s) {
    int e = 0;
    if (ax < s) {
        int ex;
        float m = frexpf(ax / s, &ex);
        int k = (m >= 0.70710678f) ? ex : ex - 1;   // f32 candidate (within +-1 of exact)
        double ax2 = (double)ax * (double)ax;       // exact
        double s2 = (double)s * (double)s;          // exact
        if (ax2 >= ldexp(s2, 2 * k + 1)) k += 1;
        else if (ax2 < ldexp(s2, 2 * k - 1)) k -= 1;
        if (k > 0) k = 0;
        e = (k < -255) ? -255 : k;
    }
    return e;
}
__device__ __forceinline__ float logq_exact(float x, float s) {
    float ax = fabsf(x);
    if (ax == 0.f) return copysignf(0.f, x);
    return copysignf(ldexpf(s, logq_e(ax, s)), x);
}

__device__ __forceinline__ void gll16(const void* g, void* l) {
    __builtin_amdgcn_global_load_lds(
        (const __attribute__((address_space(1))) void*)g,
        (__attribute__((address_space(3))) void*)l, 16, 0, 0);
}

// ---------------- scales / quant / lora prep ----------------

__global__ void k_colmax(const float* __restrict__ x, unsigned* __restrict__ smax) {
    int c = blockIdx.x * 256 + threadIdx.x;
    int r0 = blockIdx.y * 128;
    float m = 0.f;
    for (int r = 0; r < 128; ++r) m = fmaxf(m, fabsf(x[(size_t)(r0 + r) * DD + c]));
    atomicMax(smax + c, __float_as_uint(m));
}

// fused: quantize row (exact bf16 rep Ah) + lora cols + bias/pad; one pass over x
__global__ __launch_bounds__(256) void k_quant_lora(const float* __restrict__ x,
                                                    const unsigned* __restrict__ smax,
                                                    const float* __restrict__ lA,
                                                    us* __restrict__ xq) {
    __shared__ float red[4][16];
    int m = blockIdx.x, tx = threadIdx.x;
    int lane = tx & 63, w = tx >> 6;
    float4 xv = ((const float4*)(x + (size_t)m * DD))[tx];
    int c = tx * 4;
    float vv[4] = {xv.x, xv.y, xv.z, xv.w};
    ushort4 qh;
    us* ph = (us*)&qh;
#pragma unroll
    for (int j = 0; j < 4; ++j) {
        float s = fmaxf(__uint_as_float(smax[c + j]), 1e-8f);
        float sh = bf2f(f2bf(s));
        float ax = fabsf(vv[j]);
        if (ax == 0.f) ph[j] = (us)((__float_as_uint(vv[j]) >> 16) & 0x8000u);
        else ph[j] = f2bf(copysignf(ldexpf(sh, logq_e(ax, s)), vv[j]));
    }
    *(ushort4*)(xq + (size_t)m * KP + c) = qh;
    float acc[16];
#pragma unroll
    for (int r = 0; r < 16; ++r) acc[r] = 0.f;
#pragma unroll
    for (int j = 0; j < 4; ++j) {
        float xs = vv[j];
        const float4* lr = (const float4*)(lA + (size_t)(c + j) * 16);
        float4 a0 = lr[0], a1 = lr[1], a2 = lr[2], a3 = lr[3];
        acc[0] += xs * a0.x; acc[1] += xs * a0.y; acc[2] += xs * a0.z; acc[3] += xs * a0.w;
        acc[4] += xs * a1.x; acc[5] += xs * a1.y; acc[6] += xs * a1.z; acc[7] += xs * a1.w;
        acc[8] += xs * a2.x; acc[9] += xs * a2.y; acc[10] += xs * a2.z; acc[11] += xs * a2.w;
        acc[12] += xs * a3.x; acc[13] += xs * a3.y; acc[14] += xs * a3.z; acc[15] += xs * a3.w;
    }
#pragma unroll
    for (int msk = 1; msk < 64; msk <<= 1)
#pragma unroll
        for (int r = 0; r < 16; ++r) acc[r] += __shfl_xor(acc[r], msk);
    if (lane == 0)
#pragma unroll
        for (int r = 0; r < 16; ++r) red[w][r] = acc[r];
    __syncthreads();
    if (tx < 16) {
        float v = 2.0f * (red[0][tx] + red[1][tx] + red[2][tx] + red[3][tx]);
        us h, l; split2(v, h, l);
        xq[(size_t)m * KP + 1024 + tx] = h;
        xq[(size_t)m * KP + 1040 + tx] = l;
    } else if (tx == 16) {
        xq[(size_t)m * KP + 1056] = 0x3F80;   // bias col = 1.0
    } else if (tx < 48) {
        xq[(size_t)m * KP + 1040 + tx] = 0;   // pads 1057..1087
    }
}

// weight quant + fold activation-scale residual: W' = Wq*(1+rho_c); split hi/lo.
__global__ __launch_bounds__(256) void k_quant_w(const float* __restrict__ W, const float* __restrict__ lB,
                                                 const float* __restrict__ bias,
                                                 const unsigned* __restrict__ smax,
                                                 us* __restrict__ wh, us* __restrict__ wl, int Nn) {
    __shared__ float red[4];
    int n = blockIdx.x, tx = threadIdx.x;
    int lane = tx & 63, w = tx >> 6;
    float4 wv = ((const float4*)(W + (size_t)n * DD))[tx];
    float m4 = fmaxf(fmaxf(fabsf(wv.x), fabsf(wv.y)), fmaxf(fabsf(wv.z), fabsf(wv.w)));
#pragma unroll
    for (int msk = 1; msk < 64; msk <<= 1) m4 = fmaxf(m4, __shfl_xor(m4, msk));
    if (lane == 0) red[w] = m4;
    __syncthreads();
    float t = fmaxf(fmaxf(fmaxf(red[0], red[1]), fmaxf(red[2], red[3])), 1e-8f);
    float vv[4] = {wv.x, wv.y, wv.z, wv.w};
    int c = tx * 4;
    ushort4 qh, ql;
    us* ph = (us*)&qh; us* pl = (us*)&ql;
#pragma unroll
    for (int j = 0; j < 4; ++j) {
        float s = fmaxf(__uint_as_float(smax[c + j]), 1e-8f);
        float sh = bf2f(f2bf(s));
        float rho = (s - sh) / sh;
        float q = logq_exact(vv[j], t);
        float wp = q + q * rho;
        split2(wp, ph[j], pl[j]);
    }
    *(ushort4*)(wh + (size_t)n * KP + c) = qh;
    *(ushort4*)(wl + (size_t)n * KP + c) = ql;
    if (tx < 64) {
        us h = 0, l = 0;
        if (tx < 32) { int r = tx & 15; split2(lB[(size_t)r * Nn + n], h, l); }
        else if (tx == 32) split2(bias[n], h, l);
        wh[(size_t)n * KP + 1024 + tx] = h;
        wl[(size_t)n * KP + 1024 + tx] = l;
    }
}

// ---------------- GEMM: C = Ah @ (W'h + W'l)^T, 2 MFMA passes ----------------
// 8-wave (512t) BM=256 BN=128 BK=64; 2 sub-phases per K-tile; counted vmcnt(8);
// GSTAGE(t+2) overlapped with ksub1 MFMA; XOR8-granule swizzle (g ^= row&7) both-sides.
// bm = blockIdx.x (consecutive blocks share one B panel -> L2-resident), bn = blockIdx.y.
// MODE 0: linear f32 C[M][Nn].
// MODE 1: qkv epilogue — q plane f32 (C), k plane *SCL split bf16 [bh][s][64],
//         v plane split bf16 DIRECTLY in vth/vtl [bh][hd][s-permuted] (transpose fused).

template <int MODE>
__global__ __launch_bounds__(512, 2) void k_gemm(const us* __restrict__ Aq_,
                                                 const us* __restrict__ Bh_, const us* __restrict__ Bl_,
                                                 float* __restrict__ C, int Nn,
                                                 us* __restrict__ Khg, us* __restrict__ Klg,
                                                 us* __restrict__ vth, us* __restrict__ vtl) {
    __shared__ us LA[2][16384];    // A 256x64 bf16 per buf (64KB total)
    __shared__ us LBh[2][8192];    // Bh 128x64 (32KB)
    __shared__ us LBl[2][8192];    // Bl 128x64 (32KB)
    int tid = threadIdx.x;
    int bm = blockIdx.x, bn = blockIdx.y;
    int lane = tid & 63, w = tid >> 6;
    int wm = w >> 2, wn = w & 3;             // 2 x 4 wave grid; per-wave out 128x32
    int l15 = lane & 15, l4 = lane >> 4;
    int srow = tid >> 3;
    int gsrc = ((tid & 7) ^ (srow & 7)) * 8;
    const us* aP  = Aq_ + (size_t)(bm * 256 + srow) * KP + gsrc;
    const us* bhP = Bh_ + (size_t)(bn * 128 + srow) * KP + gsrc;
    const us* blP = Bl_ + (size_t)(bn * 128 + srow) * KP + gsrc;
    f32x4 zero4 = {0.f, 0.f, 0.f, 0.f};
    f32x4 acc[8][2];
#pragma unroll
    for (int i = 0; i < 8; ++i) { acc[i][0] = zero4; acc[i][1] = zero4; }

#define GSTAGE(buf, kt)                                               \
    do {                                                              \
        int k0_ = (kt) * 64;                                          \
        gll16(aP + k0_,                    &LA[(buf)][0]     + tid * 8); \
        gll16(aP + (size_t)64  * KP + k0_, &LA[(buf)][4096]  + tid * 8); \
        gll16(aP + (size_t)128 * KP + k0_, &LA[(buf)][8192]  + tid * 8); \
        gll16(aP + (size_t)192 * KP + k0_, &LA[(buf)][12288] + tid * 8); \
        gll16(bhP + k0_,                   &LBh[(buf)][0]    + tid * 8); \
        gll16(bhP + (size_t)64 * KP + k0_, &LBh[(buf)][4096] + tid * 8); \
        gll16(blP + k0_,                   &LBl[(buf)][0]    + tid * 8); \
        gll16(blP + (size_t)64 * KP + k0_, &LBl[(buf)][4096] + tid * 8); \
    } while (0)

    GSTAGE(0, 0);
    GSTAGE(1, 1);
    WAITVM(8);
    __builtin_amdgcn_s_barrier();
    __builtin_amdgcn_sched_barrier(0);

    int gsw0 = ((l4)     ^ (l15 & 7)) * 8;   // ksub0 granule (swizzled), elements
    int gsw1 = ((4 + l4) ^ (l15 & 7)) * 8;   // ksub1
    int cur = 0;
    for (int kt = 0; kt < NT64; ++kt) {
        const us* A0  = &LA[cur][0];
        const us* Bh0 = &LBh[cur][0];
        const us* Bl0 = &LBl[cur][0];
        // ---- sub-phase 0 ----
        bf16x8 a0[8], b0h[2], b0l[2];
#pragma unroll
        for (int i = 0; i < 8; ++i)
            a0[i] = *(const bf16x8*)(A0 + (wm * 128 + i * 16 + l15) * 64 + gsw0);
#pragma unroll
        for (int i = 0; i < 2; ++i) {
            b0h[i] = *(const bf16x8*)(Bh0 + (wn * 32 + i * 16 + l15) * 64 + gsw0);
            b0l[i] = *(const bf16x8*)(Bl0 + (wn * 32 + i * 16 + l15) * 64 + gsw0);
        }
        __builtin_amdgcn_s_setprio(1);
#pragma unroll
        for (int mi = 0; mi < 8; ++mi)
#pragma unroll
            for (int ni = 0; ni < 2; ++ni) {
                acc[mi][ni] = __builtin_amdgcn_mfma_f32_16x16x32_bf16(a0[mi], b0h[ni], acc[mi][ni], 0, 0, 0);
                acc[mi][ni] = __builtin_amdgcn_mfma_f32_16x16x32_bf16(a0[mi], b0l[ni], acc[mi][ni], 0, 0, 0);
            }
        __builtin_amdgcn_s_setprio(0);
        // ---- sub-phase 1 reads ----
        bf16x8 a1[8], b1h[2], b1l[2];
#pragma unroll
        for (int i = 0; i < 8; ++i)
            a1[i] = *(const bf16x8*)(A0 + (wm * 128 + i * 16 + l15) * 64 + gsw1);
#pragma unroll
        for (int i = 0; i < 2; ++i) {
            b1h[i] = *(const bf16x8*)(Bh0 + (wn * 32 + i * 16 + l15) * 64 + gsw1);
            b1l[i] = *(const bf16x8*)(Bl0 + (wn * 32 + i * 16 + l15) * 64 + gsw1);
        }
        WAITLGKM0;                          // this wave done reading buf[cur]
        __builtin_amdgcn_sched_barrier(0);
        __builtin_amdgcn_s_barrier();       // all waves done reading buf[cur]
        __builtin_amdgcn_sched_barrier(0);
        if (kt + 2 < NT64) GSTAGE(cur, kt + 2);   // restage freed buffer; overlaps MFMA below
        __builtin_amdgcn_s_setprio(1);
#pragma unroll
        for (int mi = 0; mi < 8; ++mi)
#pragma unroll
            for (int ni = 0; ni < 2; ++ni) {
                acc[mi][ni] = __builtin_amdgcn_mfma_f32_16x16x32_bf16(a1[mi], b1h[ni], acc[mi][ni], 0, 0, 0);
                acc[mi][ni] = __builtin_amdgcn_mfma_f32_16x16x32_bf16(a1[mi], b1l[ni], acc[mi][ni], 0, 0, 0);
            }
        __builtin_amdgcn_s_setprio(0);
        if (kt + 2 < NT64) { WAITVM(8); } else { WAITVM(0); }   // tile kt+1 landed
        __builtin_amdgcn_s_barrier();
        __builtin_amdgcn_sched_barrier(0);
        cur ^= 1;
    }
#undef GSTAGE

    int plane = bn >> 3;   // MODE 1 only; block-uniform
#pragma unroll
    for (int mi = 0; mi < 8; ++mi) {
#pragma unroll
        for (int ni = 0; ni < 2; ++ni) {
            int ncol = bn * 128 + wn * 32 + ni * 16 + l15;
            size_t mbase = (size_t)bm * 256 + wm * 128 + mi * 16 + l4 * 4;
            if (MODE == 0) {
#pragma unroll
                for (int rr = 0; rr < 4; ++rr)
                    C[(mbase + rr) * (size_t)Nn + ncol] = acc[mi][ni][rr];
            } else {
                int cc = ncol & 1023;
                if (plane == 0) {
#pragma unroll
                    for (int rr = 0; rr < 4; ++rr)
                        C[(mbase + rr) * DD + cc] = acc[mi][ni][rr];
                } else if (plane == 1) {
#pragma unroll
                    for (int rr = 0; rr < 4; ++rr) {
                        size_t m = mbase + rr;
                        us hh, ll; split2(acc[mi][ni][rr] * SCL, hh, ll);
                        size_t d = ((size_t)((m >> 11) * 16 + (cc >> 6)) * SS + (m & 2047)) * 64 + (cc & 63);
                        Khg[d] = hh; Klg[d] = ll;
                    }
                } else {
                    // fused V transpose+split: 4 consecutive s -> contiguous ushort4 in permuted layout
                    int bq = (int)(mbase >> 11), sq = (int)(mbase & 2047);
                    int chunk = sq >> 6, s6 = sq & 63;
                    int g = ((s6 >> 5) << 2) | ((s6 >> 2) & 3);
                    int j = ((s6 >> 4) & 1) << 2;
                    size_t dof = ((size_t)((bq << 4) + (cc >> 6)) * 64 + (cc & 63)) * SS
                               + (chunk << 6) + (g << 3) + j;
                    ushort4 vh4, vl4;
                    us* hp = (us*)&vh4; us* lp = (us*)&vl4;
#pragma unroll
                    for (int rr = 0; rr < 4; ++rr) split2(acc[mi][ni][rr], hp[rr], lp[rr]);
                    *(ushort4*)(vth + dof) = vh4;
                    *(ushort4*)(vtl + dof) = vl4;
                }
            }
        }
    }
}

// ---------------- causal flash attention; 8 waves x 16 q-rows (128/block); counted-vmcnt; defer-max ----
// output written IN-PLACE into the q plane; K plane pre-scaled by SCL.
// grid (64 bh, 16 y), qt = 15-y (heavy first); 1024 blocks = 2 dispatch rounds -> dynamic balance.

__global__ __launch_bounds__(512, 2) void k_attn(float* qo,
                                                 const us* __restrict__ Khg, const us* __restrict__ Klg,
                                                 const us* __restrict__ vth, const us* __restrict__ vtl) {
    __shared__ us L[2][16384];  // per buf: [0]=Kh [4096]=Kl [8192]=Vh [12288]=Vl, 64x64 bf16, XOR-8 swz
    int bh = blockIdx.x;
    int qt = (int)(gridDim.y - 1) - blockIdx.y;   // heavy q-tiles first
    int b = bh >> 4, h = bh & 15;
    int q0 = qt * 128;
    int tid = threadIdx.x, w = tid >> 6, lane = tid & 63;
    int l15 = lane & 15, l4 = lane >> 4;
    int qw = q0 + w * 16;          // wave owns 16 q rows
    int swz = l15 & 7;

    bf16x8 qh[2], ql[2];
#pragma unroll
    for (int hf = 0; hf < 2; ++hf) {
        const float* qp = qo + (size_t)(b * SS + qw + l15) * DD + h * 64 + hf * 32 + l4 * 8;
        float4 a = *(const float4*)qp;
        float4 c = *(const float4*)(qp + 4);
        float vv[8] = {a.x, a.y, a.z, a.w, c.x, c.y, c.z, c.w};
        bf16x8 hq, lq;
#pragma unroll
        for (int j = 0; j < 8; ++j) {
            us hh = f2bf(vv[j]);
            hq[j] = (short)hh;
            lq[j] = (short)f2bf(vv[j] - bf2f(hh));
        }
        qh[hf] = hq; ql[hf] = lq;
    }

    f32x4 zero4 = {0.f, 0.f, 0.f, 0.f};
    f32x4 of[4];
#pragma unroll
    for (int j = 0; j < 4; ++j) of[j] = zero4;
    float mrow = -1e30f, lrowp = 0.f;   // per-lane partial sum

    int r0 = tid >> 3, sl0 = (tid & 7) ^ (r0 & 7);
    int koff0 = (bh * SS + r0) * 64 + sl0 * 8;
    int voff0 = (bh * 64 + r0) * SS + sl0 * 8;

    int ntiles = qt * 2 + 2;

#define STAGE(buf, tt)                                           \
    do {                                                         \
        int kv_ = (tt) * 64;                                     \
        us* D_ = &L[(buf)][0];                                   \
        int kadd_ = kv_ << 6;                                    \
        gll16(Khg + koff0 + kadd_, D_ + tid * 8);                \
        gll16(Klg + koff0 + kadd_, D_ + 4096 + tid * 8);         \
        gll16(vth + voff0 + kv_, D_ + 8192 + tid * 8);           \
        gll16(vtl + voff0 + kv_, D_ + 12288 + tid * 8);          \
    } while (0)

    STAGE(0, 0);
    STAGE(1, 1);
    int cur = 0;

    for (int t = 0; t < ntiles; ++t) {
        int kv0 = t * 64;
        if (t + 1 < ntiles) { WAITVM(4); } else { WAITVM(0); }
        __builtin_amdgcn_s_barrier();

        if (kv0 <= qw + 15) {
            const us* Lc = &L[cur][0];

            f32x4 sf[4];
#pragma unroll
            for (int i = 0; i < 4; ++i) sf[i] = zero4;
            __builtin_amdgcn_s_setprio(1);
#pragma unroll
            for (int kb = 0; kb < 4; ++kb) {
                int rbase = (kb * 16 + l15) * 64;
#pragma unroll
                for (int hf = 0; hf < 2; ++hf) {
                    int off = rbase + (((hf * 4 + l4) ^ swz) * 8);
                    bf16x8 kh = *(const bf16x8*)(Lc + off);
                    bf16x8 kl = *(const bf16x8*)(Lc + 4096 + off);
                    sf[kb] = __builtin_amdgcn_mfma_f32_16x16x32_bf16(kh, qh[hf], sf[kb], 0, 0, 0);
                    sf[kb] = __builtin_amdgcn_mfma_f32_16x16x32_bf16(kh, ql[hf], sf[kb], 0, 0, 0);
                    sf[kb] = __builtin_amdgcn_mfma_f32_16x16x32_bf16(kl, qh[hf], sf[kb], 0, 0, 0);
                }
            }
            __builtin_amdgcn_s_setprio(0);

            bool diag = (kv0 + 63 > qw);   // wave-uniform
            u32x4 PH[2], PL[2];
            {
                float pv[16];
                if (diag) {
                    int qg = qw + l15;
#pragma unroll
                    for (int kb = 0; kb < 4; ++kb)
#pragma unroll
                        for (int rr = 0; rr < 4; ++rr) {
                            int kvg = kv0 + kb * 16 + l4 * 4 + rr;
                            pv[kb * 4 + rr] = (kvg > qg) ? -1e30f : sf[kb][rr];
                        }
                } else {
#pragma unroll
                    for (int kb = 0; kb < 4; ++kb)
#pragma unroll
                        for (int rr = 0; rr < 4; ++rr)
                            pv[kb * 4 + rr] = sf[kb][rr];
                }
                float t0 = fmaxf(fmaxf(pv[0], pv[1]), pv[2]);
                float t1 = fmaxf(fmaxf(pv[3], pv[4]), pv[5]);
                float t2 = fmaxf(fmaxf(pv[6], pv[7]), pv[8]);
                float t3 = fmaxf(fmaxf(pv[9], pv[10]), pv[11]);
                float t4 = fmaxf(fmaxf(pv[12], pv[13]), pv[14]);
                float tmax = fmaxf(fmaxf(fmaxf(t0, t1), fmaxf(t2, t3)), fmaxf(t4, pv[15]));
                tmax = fmaxf(tmax, __shfl_xor(tmax, 16));
                tmax = fmaxf(tmax, __shfl_xor(tmax, 32));
                float mcur = mrow;
                if (!__all(tmax <= mcur + 8.0f)) {   // defer-max: exact (fac==1 when skipped)
                    float mnew = fmaxf(mcur, tmax);
                    float fac = __builtin_amdgcn_exp2f(mcur - mnew);
                    mrow = mnew; mcur = mnew;
                    lrowp *= fac;
                    float fr0 = __shfl(fac, l4 * 4 + 0);
                    float fr1 = __shfl(fac, l4 * 4 + 1);
                    float fr2 = __shfl(fac, l4 * 4 + 2);
                    float fr3 = __shfl(fac, l4 * 4 + 3);
#pragma unroll
                    for (int hb = 0; hb < 4; ++hb) {
                        of[hb][0] *= fr0; of[hb][1] *= fr1;
                        of[hb][2] *= fr2; of[hb][3] *= fr3;
                    }
                }
                float ps = 0.f;
#pragma unroll
                for (int i = 0; i < 16; ++i) {
                    pv[i] = __builtin_amdgcn_exp2f(pv[i] - mcur);
                    ps += pv[i];
                }
                lrowp += ps;                 // per-lane partial; cross-lane at epilogue
#pragma unroll
                for (int ks = 0; ks < 2; ++ks)
#pragma unroll
                    for (int c2 = 0; c2 < 4; ++c2) {
                        float p0 = pv[ks * 8 + c2 * 2], p1 = pv[ks * 8 + c2 * 2 + 1];
                        unsigned u = cvtpk(p0, p1);
                        float h0 = __uint_as_float(u << 16);
                        float h1 = __uint_as_float(u & 0xffff0000u);
                        unsigned ul = cvtpk(p0 - h0, p1 - h1);
                        PH[ks][c2] = u; PL[ks][c2] = ul;
                    }
            }

            __builtin_amdgcn_s_setprio(1);
#pragma unroll
            for (int hb = 0; hb < 4; ++hb) {
                int rbase = (hb * 16 + l15) * 64;
#pragma unroll
                for (int ks = 0; ks < 2; ++ks) {
                    int off = rbase + (((ks * 4 + l4) ^ swz) * 8);
                    bf16x8 vh = *(const bf16x8*)(Lc + 8192 + off);
                    bf16x8 vl = *(const bf16x8*)(Lc + 12288 + off);
                    bf16x8 pa = (bf16x8)PH[ks];
                    bf16x8 pb = (bf16x8)PL[ks];
                    of[hb] = __builtin_amdgcn_mfma_f32_16x16x32_bf16(pa, vh, of[hb], 0, 0, 0);
                    of[hb] = __builtin_amdgcn_mfma_f32_16x16x32_bf16(pa, vl, of[hb], 0, 0, 0);
                    of[hb] = __builtin_amdgcn_mfma_f32_16x16x32_bf16(pb, vh, of[hb], 0, 0, 0);
                }
            }
            __builtin_amdgcn_s_setprio(0);
        }

        __builtin_amdgcn_s_barrier();
        if (t + 2 < ntiles) STAGE(cur, t + 2);
        cur ^= 1;
    }
#undef STAGE

    {
        float lr = lrowp;
        lr += __shfl_xor(lr, 16);
        lr += __shfl_xor(lr, 32);
        float linv = 1.f / lr;
        float f0 = __shfl(linv, l4 * 4 + 0);
        float f1 = __shfl(linv, l4 * 4 + 1);
        float f2 = __shfl(linv, l4 * 4 + 2);
        float f3 = __shfl(linv, l4 * 4 + 3);
        int qgb = qw + l4 * 4;
#pragma unroll
        for (int hb = 0; hb < 4; ++hb) {
            int col = h * 64 + hb * 16 + l15;
            qo[((size_t)(b * SS + qgb + 0)) * DD + col] = of[hb][0] * f0;
            qo[((size_t)(b * SS + qgb + 1)) * DD + col] = of[hb][1] * f1;
            qo[((size_t)(b * SS + qgb + 2)) * DD + col] = of[hb][2] * f2;
            qo[((size_t)(b * SS + qgb + 3)) * DD + col] = of[hb][3] * f3;
        }
    }
}

// ---------------- launcher ----------------

extern "C" void kernel_launch(void* const* d_in, const int* in_sizes, int n_in,
                              void* d_out, int out_size, void* d_ws, size_t ws_size,
                              hipStream_t stream) {
    const float* hidden  = (const float*)d_in[0];
    const float* W_attn  = (const float*)d_in[2];
    const float* b_attn  = (const float*)d_in[3];
    const float* lA_attn = (const float*)d_in[4];
    const float* lB_attn = (const float*)d_in[5];
    const float* W_proj  = (const float*)d_in[6];
    const float* b_proj  = (const float*)d_in[7];
    const float* lA_proj = (const float*)d_in[8];
    const float* lB_proj = (const float*)d_in[9];
    float* out = (float*)d_out;

    char* ws = (char*)d_ws;
    unsigned* s1 = (unsigned*)(ws);
    unsigned* s2 = (unsigned*)(ws + 4096);
    us* xq  = (us*)(ws + 8192);                              // 17,825,792 B (8192x1088x2)
    us* wh1 = (us*)(ws + 8192 + 17825792);                   // 6,684,672
    us* wl1 = (us*)(ws + 8192 + 17825792 + 6684672);         // 6,684,672
    us* wh2 = (us*)(ws + 8192 + 17825792 + 2 * 6684672);     // 2,228,224
    us* wl2 = (us*)(ws + 8192 + 17825792 + 2 * 6684672 + 2228224);
    char* pbase = ws + 8192 + 17825792 + 2 * 6684672 + 2 * 2228224;
    float* qbuf = (float*)pbase;                             // 33,554,432 (q plane; attn out in-place)
    us* vth = (us*)(pbase + 33554432);                       // 16,777,216 (written by gemm<1> epilogue)
    us* vtl = (us*)(pbase + 33554432 + 16777216);            // 16,777,216
    us* Khg = (us*)(pbase + 33554432 + 2 * (size_t)16777216);
    us* Klg = (us*)(pbase + 33554432 + 3 * (size_t)16777216);

    hipMemsetAsync(ws, 0, 8192, stream);   // zero s1 + s2

    // ---- qkv projection (V transposed+split in epilogue) ----
    k_colmax<<<dim3(4, 64), 256, 0, stream>>>(hidden, s1);
    k_quant_lora<<<MTOT, 256, 0, stream>>>(hidden, s1, lA_attn, xq);
    k_quant_w<<<3072, 256, 0, stream>>>(W_attn, lB_attn, b_attn, s1, wh1, wl1, 3072);
    k_gemm<1><<<dim3(32, 24), 512, 0, stream>>>(xq, wh1, wl1, qbuf, DQKV, Khg, Klg, vth, vtl);

    // ---- attention (output in-place into qbuf) ----
    k_attn<<<dim3(64, 16), 512, 0, stream>>>(qbuf, Khg, Klg, vth, vtl);

    // ---- output projection ----
    k_colmax<<<dim3(4, 64), 256, 0, stream>>>(qbuf, s2);
    k_quant_lora<<<MTOT, 256, 0, stream>>>(qbuf, s2, lA_proj, xq);
    k_quant_w<<<1024, 256, 0, stream>>>(W_proj, lB_proj, b_proj, s2, wh2, wl2, 1024);
    k_gemm<0><<<dim3(32, 8), 512, 0, stream>>>(xq, wh2, wl2, out, DD, nullptr, nullptr, nullptr, nullptr);
}